// Round 1
// baseline (36.106 us; speedup 1.0000x reference)
//
#include <hip/hip_runtime.h>

#define BLOCK 256
#define GRID  1280          // 5 blocks/CU * 256 CUs (LDS-limited occupancy: 28KB/block)
#define NB_MAX 5000
#define NP_MAX 2000

__global__ __launch_bounds__(BLOCK) void vs_ll_kernel(
    const float* __restrict__ v1, const float* __restrict__ v2,
    const float* __restrict__ weight,
    const float* __restrict__ e1, const float* __restrict__ e2,
    const int*  __restrict__ bidx, const int* __restrict__ pidx,
    int nb, int np, int n, float* __restrict__ partials)
{
    __shared__ float s_v1[NB_MAX];
    __shared__ float s_v2[NP_MAX];
    __shared__ float s_red[BLOCK / 64];

    // stage gather tables into LDS (coalesced)
    for (int i = threadIdx.x; i < nb; i += BLOCK) s_v1[i] = v1[i];
    for (int i = threadIdx.x; i < np; i += BLOCK) s_v2[i] = v2[i];
    __syncthreads();

    const float w     = weight[0];
    const float onemw = 1.0f - w;
    const float LOG_LO = -13.815511f;      // log(1e-6)
    const float LOG_HI = -1.0000005e-6f;   // log(0.999999)

    float acc = 0.0f;

    const int n4     = n >> 2;
    const int gid    = blockIdx.x * BLOCK + threadIdx.x;
    const int stride = GRID * BLOCK;
    const float4* e1v = (const float4*)e1;
    const float4* e2v = (const float4*)e2;
    const int4*   bv  = (const int4*)bidx;
    const int4*   pv  = (const int4*)pidx;

    for (int i = gid; i < n4; i += stride) {
        float4 a = e1v[i];
        float4 c = e2v[i];
        int4   b = bv[i];
        int4   p = pv[i];

        float bb[4] = { s_v1[b.x], s_v1[b.y], s_v1[b.z], s_v1[b.w] };
        float pp[4] = { s_v2[p.x], s_v2[p.y], s_v2[p.z], s_v2[p.w] };
        float u1[4] = { a.x, a.y, a.z, a.w };
        float u2[4] = { c.x, c.y, c.z, c.w };

        #pragma unroll
        for (int j = 0; j < 4; ++j) {
            float z  = fmaf(w, bb[j], onemw * pp[j]);
            float az = fabsf(z);
            // l = log1p(exp(-|z|)); fast log is fine: per-term abs err < 1e-6,
            // 10M-term sum err << 1.6e5 threshold.
            float l  = __logf(1.0f + __expf(-az));
            float logp = -(fmaxf(-z, 0.0f) + l);   // log(sigmoid(z))
            float logq = -(fmaxf( z, 0.0f) + l);   // log(1 - sigmoid(z))
            logp = fminf(fmaxf(logp, LOG_LO), LOG_HI);
            logq = fminf(fmaxf(logq, LOG_LO), LOG_HI);
            acc = fmaf(u1[j], logp, acc);
            acc = fmaf(u2[j], logq, acc);
        }
    }

    // scalar tail (n % 4, normally 0)
    for (int i = (n4 << 2) + gid; i < n; i += stride) {
        float z  = fmaf(w, s_v1[bidx[i]], onemw * s_v2[pidx[i]]);
        float az = fabsf(z);
        float l  = __logf(1.0f + __expf(-az));
        float logp = fminf(fmaxf(-(fmaxf(-z, 0.0f) + l), LOG_LO), LOG_HI);
        float logq = fminf(fmaxf(-(fmaxf( z, 0.0f) + l), LOG_LO), LOG_HI);
        acc = fmaf(e1[i], logp, acc);
        acc = fmaf(e2[i], logq, acc);
    }

    // wave reduce (64 lanes)
    #pragma unroll
    for (int off = 32; off > 0; off >>= 1)
        acc += __shfl_down(acc, off, 64);

    const int lane = threadIdx.x & 63;
    const int wid  = threadIdx.x >> 6;
    if (lane == 0) s_red[wid] = acc;
    __syncthreads();
    if (threadIdx.x == 0) {
        float t = 0.0f;
        #pragma unroll
        for (int k = 0; k < BLOCK / 64; ++k) t += s_red[k];
        partials[blockIdx.x] = t;
    }
}

__global__ __launch_bounds__(BLOCK) void vs_reduce_kernel(
    const float* __restrict__ partials, int nparts, float* __restrict__ out)
{
    __shared__ float s_red[BLOCK / 64];
    float acc = 0.0f;
    for (int i = threadIdx.x; i < nparts; i += BLOCK) acc += partials[i];
    #pragma unroll
    for (int off = 32; off > 0; off >>= 1)
        acc += __shfl_down(acc, off, 64);
    const int lane = threadIdx.x & 63;
    const int wid  = threadIdx.x >> 6;
    if (lane == 0) s_red[wid] = acc;
    __syncthreads();
    if (threadIdx.x == 0) {
        float t = 0.0f;
        #pragma unroll
        for (int k = 0; k < BLOCK / 64; ++k) t += s_red[k];
        out[0] = t;
    }
}

extern "C" void kernel_launch(void* const* d_in, const int* in_sizes, int n_in,
                              void* d_out, int out_size, void* d_ws, size_t ws_size,
                              hipStream_t stream) {
    const float* v1     = (const float*)d_in[0];
    const float* v2     = (const float*)d_in[1];
    const float* weight = (const float*)d_in[2];
    const float* e1     = (const float*)d_in[3];
    const float* e2     = (const float*)d_in[4];
    const int*   bidx   = (const int*)d_in[5];
    const int*   pidx   = (const int*)d_in[6];

    const int nb = in_sizes[0];
    const int np = in_sizes[1];
    const int n  = in_sizes[3];

    float* partials = (float*)d_ws;
    float* out      = (float*)d_out;

    vs_ll_kernel<<<GRID, BLOCK, 0, stream>>>(v1, v2, weight, e1, e2, bidx, pidx,
                                             nb, np, n, partials);
    vs_reduce_kernel<<<1, BLOCK, 0, stream>>>(partials, GRID, out);
}

// Round 2
// 34.192 us; speedup vs baseline: 1.0560x; 1.0560x over previous
//
#include <hip/hip_runtime.h>

#define BLOCK 512
#define GRID  1024          // 4 blocks/CU * 256 CUs -> 32 waves/CU (LDS 28KB/block)
#define NB_MAX 5000
#define NP_MAX 2000

__global__ __launch_bounds__(BLOCK, 8) void vs_ll_kernel(
    const float* __restrict__ v1, const float* __restrict__ v2,
    const float* __restrict__ weight,
    const float* __restrict__ e1, const float* __restrict__ e2,
    const int*  __restrict__ bidx, const int* __restrict__ pidx,
    int nb, int np, int n, float* __restrict__ partials)
{
    __shared__ float s_v1[NB_MAX];
    __shared__ float s_v2[NP_MAX];
    __shared__ float s_red[BLOCK / 64];

    // stage gather tables into LDS (coalesced)
    for (int i = threadIdx.x; i < nb; i += BLOCK) s_v1[i] = v1[i];
    for (int i = threadIdx.x; i < np; i += BLOCK) s_v2[i] = v2[i];
    __syncthreads();

    const float w     = weight[0];
    const float onemw = 1.0f - w;
    const float LOG_LO = -13.815511f;      // log(1e-6)
    const float LOG_HI = -1.0000005e-6f;   // log(0.999999)

    float acc = 0.0f;

    const int n4     = n >> 2;
    const int gid    = blockIdx.x * BLOCK + threadIdx.x;
    const int stride = GRID * BLOCK;
    const float4* e1v = (const float4*)e1;
    const float4* e2v = (const float4*)e2;
    const int4*   bv  = (const int4*)bidx;
    const int4*   pv  = (const int4*)pidx;

    // software-pipelined grid-stride loop: loads for iter k+1 issue
    // before compute of iter k (hides L3/HBM latency under VALU work)
    int  i     = gid;
    bool valid = (i < n4);
    float4 a, c; int4 b, p;
    if (valid) { a = e1v[i]; c = e2v[i]; b = bv[i]; p = pv[i]; }

    while (valid) {
        const int  inext = i + stride;
        const bool vnext = (inext < n4);
        float4 a2, c2; int4 b2, p2;
        if (vnext) { a2 = e1v[inext]; c2 = e2v[inext]; b2 = bv[inext]; p2 = pv[inext]; }

        float bb[4] = { s_v1[b.x], s_v1[b.y], s_v1[b.z], s_v1[b.w] };
        float pp[4] = { s_v2[p.x], s_v2[p.y], s_v2[p.z], s_v2[p.w] };
        float u1[4] = { a.x, a.y, a.z, a.w };
        float u2[4] = { c.x, c.y, c.z, c.w };

        #pragma unroll
        for (int j = 0; j < 4; ++j) {
            float z  = fmaf(w, bb[j], onemw * pp[j]);
            float az = fabsf(z);
            // l = log1p(exp(-|z|)); fast log fine: per-term abs err < 1e-6,
            // 10M-term sum err << 1.6e5 threshold.
            float l  = __logf(1.0f + __expf(-az));
            float logp = -(fmaxf(-z, 0.0f) + l);   // log(sigmoid(z))
            float logq = -(fmaxf( z, 0.0f) + l);   // log(1 - sigmoid(z))
            logp = fminf(fmaxf(logp, LOG_LO), LOG_HI);
            logq = fminf(fmaxf(logq, LOG_LO), LOG_HI);
            acc = fmaf(u1[j], logp, acc);
            acc = fmaf(u2[j], logq, acc);
        }

        a = a2; c = c2; b = b2; p = p2;
        i = inext; valid = vnext;
    }

    // scalar tail (n % 4, normally 0)
    for (int t = (n4 << 2) + gid; t < n; t += stride) {
        float z  = fmaf(w, s_v1[bidx[t]], onemw * s_v2[pidx[t]]);
        float az = fabsf(z);
        float l  = __logf(1.0f + __expf(-az));
        float logp = fminf(fmaxf(-(fmaxf(-z, 0.0f) + l), LOG_LO), LOG_HI);
        float logq = fminf(fmaxf(-(fmaxf( z, 0.0f) + l), LOG_LO), LOG_HI);
        acc = fmaf(e1[t], logp, acc);
        acc = fmaf(e2[t], logq, acc);
    }

    // wave reduce (64 lanes)
    #pragma unroll
    for (int off = 32; off > 0; off >>= 1)
        acc += __shfl_down(acc, off, 64);

    const int lane = threadIdx.x & 63;
    const int wid  = threadIdx.x >> 6;
    if (lane == 0) s_red[wid] = acc;
    __syncthreads();
    if (threadIdx.x == 0) {
        float t = 0.0f;
        #pragma unroll
        for (int k = 0; k < BLOCK / 64; ++k) t += s_red[k];
        partials[blockIdx.x] = t;
    }
}

__global__ __launch_bounds__(256) void vs_reduce_kernel(
    const float* __restrict__ partials, int nparts, float* __restrict__ out)
{
    __shared__ float s_red[4];
    float acc = 0.0f;
    for (int i = threadIdx.x; i < nparts; i += 256) acc += partials[i];
    #pragma unroll
    for (int off = 32; off > 0; off >>= 1)
        acc += __shfl_down(acc, off, 64);
    const int lane = threadIdx.x & 63;
    const int wid  = threadIdx.x >> 6;
    if (lane == 0) s_red[wid] = acc;
    __syncthreads();
    if (threadIdx.x == 0) {
        float t = 0.0f;
        #pragma unroll
        for (int k = 0; k < 4; ++k) t += s_red[k];
        out[0] = t;
    }
}

extern "C" void kernel_launch(void* const* d_in, const int* in_sizes, int n_in,
                              void* d_out, int out_size, void* d_ws, size_t ws_size,
                              hipStream_t stream) {
    const float* v1     = (const float*)d_in[0];
    const float* v2     = (const float*)d_in[1];
    const float* weight = (const float*)d_in[2];
    const float* e1     = (const float*)d_in[3];
    const float* e2     = (const float*)d_in[4];
    const int*   bidx   = (const int*)d_in[5];
    const int*   pidx   = (const int*)d_in[6];

    const int nb = in_sizes[0];
    const int np = in_sizes[1];
    const int n  = in_sizes[3];

    float* partials = (float*)d_ws;
    float* out      = (float*)d_out;

    vs_ll_kernel<<<GRID, BLOCK, 0, stream>>>(v1, v2, weight, e1, e2, bidx, pidx,
                                             nb, np, n, partials);
    vs_reduce_kernel<<<1, 256, 0, stream>>>(partials, GRID, out);
}